// Round 3
// baseline (82.768 us; speedup 1.0000x reference)
//
#include <hip/hip_runtime.h>
#include <hip/hip_bf16.h>
#include <stdint.h>

typedef __attribute__((ext_vector_type(8))) short short8;
typedef __attribute__((ext_vector_type(4))) float f32x4;
typedef __attribute__((ext_vector_type(4))) unsigned uint4v;

#define NB 8
#define NN 2048
#define CC 256
#define LP1 4097
#define HR 192
#define PDim 16
#define KP 224          /* padded K for pair GEMM: 208 real + 16 zero */
#define NPAD 448
#define HEAD_SCALE 0.17677669529663689f  /* 1/sqrt(32) */

#define GLOAD16(g, l) __builtin_amdgcn_global_load_lds( \
    (const __attribute__((address_space(1))) unsigned int*)(g), \
    (__attribute__((address_space(3))) unsigned int*)(l), 16, 0, 0)

// ---------------- K0: prep (vectorized) ----------------
// xb (16384 x 256 bf16) = folded x; WT (448 x 256 bf16, Q pre-scaled);
// zero-fill P/R K-pad cols [208,224).
__global__ __launch_bounds__(256) void k0_prep(
    const float* __restrict__ feats,
    const float* __restrict__ Wq, const float* __restrict__ Wk,
    const float* __restrict__ Wpi, const float* __restrict__ Wpj,
    const float* __restrict__ Wd,
    __hip_bfloat16* __restrict__ xb, __hip_bfloat16* __restrict__ WT,
    unsigned* __restrict__ Ppad, unsigned* __restrict__ Rpad)
{
    const int XV   = NB*NN*CC/8;   // 524288 short8 items
    const int WTN  = NPAD*CC;      // 114688
    const int PV   = NB*NN*2;      // 32768 uint4 items per array
    const int TOT  = XV + WTN + 2*PV;
    int stride = gridDim.x * blockDim.x;
    for (int i = blockIdx.x*blockDim.x + threadIdx.x; i < TOT; i += stride) {
        if (i < XV) {
            int grow = i >> 5, kk = (i & 31) << 3;
            int b = grow >> 11, n = grow & (NN-1);
            size_t base = ((size_t)b*LP1 + 1 + 2*n)*CC + kk;
            float4 a0 = *(const float4*)(feats + base);
            float4 a1 = *(const float4*)(feats + base + 4);
            float4 c0 = *(const float4*)(feats + base + CC);
            float4 c1 = *(const float4*)(feats + base + CC + 4);
            __hip_bfloat16 h[8];
            h[0] = __float2bfloat16(0.5f*(a0.x + c0.x));
            h[1] = __float2bfloat16(0.5f*(a0.y + c0.y));
            h[2] = __float2bfloat16(0.5f*(a0.z + c0.z));
            h[3] = __float2bfloat16(0.5f*(a0.w + c0.w));
            h[4] = __float2bfloat16(0.5f*(a1.x + c1.x));
            h[5] = __float2bfloat16(0.5f*(a1.y + c1.y));
            h[6] = __float2bfloat16(0.5f*(a1.z + c1.z));
            h[7] = __float2bfloat16(0.5f*(a1.w + c1.w));
            *(short8*)(xb + (size_t)grow*CC + kk) = *(const short8*)h;
        } else if (i < XV + WTN) {
            int j = i - XV;
            int c = j >> 8, k = j & 255;
            float v;
            if (c < HR)                 v = Wq[k*HR + c] * HEAD_SCALE;
            else if (c < 2*HR)          v = Wk[k*HR + (c-HR)];
            else if (c < 2*HR+PDim)     v = Wpi[k*PDim + (c-2*HR)];
            else if (c < 2*HR+2*PDim)   v = Wpj[k*PDim + (c-2*HR-PDim)];
            else if (c == 416)          v = Wd[k];
            else                        v = 0.f;
            WT[j] = __float2bfloat16(v);
        } else {
            int j = i - XV - WTN;
            unsigned* arr = (j < PV) ? Ppad : Rpad;
            int q = (j < PV) ? j : j - PV;
            int row = q >> 1, of = 104 + (q & 1)*4;   // uint cols [104,112)
            *(uint4v*)(arr + (size_t)row*(KP/2) + of) = (uint4v){0,0,0,0};
        }
    }
}

// ---------------- KA: projection GEMM ----------------
// (16384 x 256) x (256 x 448). Block = 32 rows x 448 cols, 512 blocks.
__global__ __launch_bounds__(256, 4) void ka_proj(
    const __hip_bfloat16* __restrict__ xb, const __hip_bfloat16* __restrict__ WT,
    const float* __restrict__ bpi, const float* __restrict__ bpj,
    const float* __restrict__ bd, const float* __restrict__ alpha_pair,
    __hip_bfloat16* __restrict__ P, __hip_bfloat16* __restrict__ R,
    float* __restrict__ dvec)
{
    int t = threadIdx.x;
    int lane = t & 63;
    int w = t >> 6;
    int l15 = lane & 15, lg = lane >> 4;
    int row0 = blockIdx.x * 32;

    const __hip_bfloat16* pA[2];
    const __hip_bfloat16* pB[7];
#pragma unroll
    for (int mi = 0; mi < 2; ++mi)
        pA[mi] = xb + (size_t)(row0 + mi*16 + l15)*CC + lg*8;
#pragma unroll
    for (int ni = 0; ni < 7; ++ni)
        pB[ni] = WT + (size_t)(w*112 + ni*16 + l15)*CC + lg*8;

    f32x4 acc[2][7];
#pragma unroll
    for (int mi = 0; mi < 2; ++mi)
#pragma unroll
        for (int ni = 0; ni < 7; ++ni)
            acc[mi][ni] = (f32x4){0.f, 0.f, 0.f, 0.f};

#pragma unroll
    for (int kk = 0; kk < 8; ++kk) {
        short8 a[2], bb[7];
#pragma unroll
        for (int mi = 0; mi < 2; ++mi) a[mi] = *(const short8*)(pA[mi] + kk*32);
#pragma unroll
        for (int ni = 0; ni < 7; ++ni) bb[ni] = *(const short8*)(pB[ni] + kk*32);
#pragma unroll
        for (int mi = 0; mi < 2; ++mi)
#pragma unroll
            for (int ni = 0; ni < 7; ++ni)
                acc[mi][ni] = __builtin_amdgcn_mfma_f32_16x16x32_bf16(
                    a[mi], bb[ni], acc[mi][ni], 0, 0, 0);
    }

    float alpha_eff = fmaxf(alpha_pair[0], 0.f);
    float bd0 = bd[0];
#pragma unroll
    for (int mi = 0; mi < 2; ++mi) {
#pragma unroll
        for (int ni = 0; ni < 7; ++ni) {
            int c = w*112 + ni*16 + l15;
#pragma unroll
            for (int j = 0; j < 4; ++j) {
                int r = mi*16 + lg*4 + j;
                int grow = row0 + r;
                int b = grow >> 11, n = grow & (NN-1);
                size_t rb = ((size_t)b*NN + n)*KP;
                float v = acc[mi][ni][j];
                if (c < HR) {
                    P[rb + c] = __float2bfloat16(v);           // Q*HEAD_SCALE (in WT)
                } else if (c < 2*HR) {
                    R[rb + (c-HR)] = __float2bfloat16(v);      // K
                } else if (c < 2*HR+PDim) {
                    int pc = c - 2*HR;
                    P[rb + HR + pc] = __float2bfloat16(fmaxf(v + bpi[pc], 0.f) * alpha_eff);
                } else if (c < 2*HR+2*PDim) {
                    int pc = c - 2*HR - PDim;
                    R[rb + HR + pc] = __float2bfloat16(fmaxf(v + bpj[pc], 0.f));
                } else if (c == 416) {
                    dvec[(size_t)b*NN + n] = v + bd0;
                }
            }
        }
    }
}

// ---------------- KB: batched pair GEMM ----------------
// S[b] = P[b] (2048x224) x R[b]^T + diag(d), * max(logit_scale,0.01).
// 1-D grid 2048: batch = hwid&7 (all 256 blocks of a batch land on one XCD,
// so its 3.5 MB P+R stays in that XCD's private L2). Nontemporal C-stores
// keep the 134 MB write stream from evicting P/R.
__global__ __launch_bounds__(256, 4) void kb_pair(
    const __hip_bfloat16* __restrict__ P, const __hip_bfloat16* __restrict__ R,
    const float* __restrict__ dvec, const float* __restrict__ logit_scale,
    float* __restrict__ out)
{
    __shared__ __hip_bfloat16 ldsA[2][128*32];
    __shared__ __hip_bfloat16 ldsB[2][128*32];

    int t = threadIdx.x;
    int lane = t & 63;
    int w = t >> 6;
    int wr = w >> 1, wc = w & 1;
    int l15 = lane & 15, lg = lane >> 4;

    int hw = blockIdx.x;
    int b = hw & 7;                 // batch <-> XCD affinity
    int within = hw >> 3;           // 0..255
    int m0 = (within & 15) << 7;    // output cols (R rows)
    int n0 = (within >> 4) << 7;    // output rows (P rows)

    // staging source addrs (pre-swizzled). inst i: LDS byte = i*4096 + t*16
    // -> row = i*64 + (t>>2), colb = (t&3)*16; src colb = colb ^ ((row&3)<<4)
    const char* srcA[2];
    const char* srcB[2];
#pragma unroll
    for (int i = 0; i < 2; ++i) {
        int row   = i*64 + (t >> 2);
        int scolb = ((t & 3) << 4) ^ ((row & 3) << 4);
        srcA[i] = (const char*)(P + ((size_t)b*NN + n0 + row)*KP) + scolb;
        srcB[i] = (const char*)(R + ((size_t)b*NN + m0 + row)*KP) + scolb;
    }
    int ldst = w * 1024;   // wave-uniform LDS dest base (+ lane*16 by HW)

    // ds_read byte offsets (swizzled): row*64 + 16*(lg ^ (row&3)), + frag*1024
    int abyte = (wr*64 + l15)*64 + ((lg ^ (l15 & 3)) << 4);
    int bbyte = (wc*64 + l15)*64 + ((lg ^ (l15 & 3)) << 4);

    f32x4 acc[4][4];
#pragma unroll
    for (int mi = 0; mi < 4; ++mi)
#pragma unroll
        for (int ni = 0; ni < 4; ++ni)
            acc[mi][ni] = (f32x4){0.f, 0.f, 0.f, 0.f};

    // prologue: stage K-step 0 into buf 0
#pragma unroll
    for (int i = 0; i < 2; ++i) {
        GLOAD16(srcA[i], (char*)(&ldsA[0][0]) + i*4096 + ldst);
        GLOAD16(srcB[i], (char*)(&ldsB[0][0]) + i*4096 + ldst);
    }

    int buf = 0;
#pragma unroll
    for (int s = 0; s < 7; ++s) {   // 7 K-steps of 32 (KP=224)
        __syncthreads();
        if (s < 6) {
            size_t kof = (size_t)(s + 1) * 64;
#pragma unroll
            for (int i = 0; i < 2; ++i) {
                GLOAD16(srcA[i] + kof, (char*)(&ldsA[buf ^ 1][0]) + i*4096 + ldst);
                GLOAD16(srcB[i] + kof, (char*)(&ldsB[buf ^ 1][0]) + i*4096 + ldst);
            }
        }
        short8 a[4], bb[4];
#pragma unroll
        for (int mi = 0; mi < 4; ++mi)
            a[mi] = *(const short8*)((const char*)(&ldsA[buf][0]) + abyte + mi*1024);
#pragma unroll
        for (int ni = 0; ni < 4; ++ni)
            bb[ni] = *(const short8*)((const char*)(&ldsB[buf][0]) + bbyte + ni*1024);
#pragma unroll
        for (int mi = 0; mi < 4; ++mi)
#pragma unroll
            for (int ni = 0; ni < 4; ++ni)
                acc[mi][ni] = __builtin_amdgcn_mfma_f32_16x16x32_bf16(
                    a[mi], bb[ni], acc[mi][ni], 0, 0, 0);
        buf ^= 1;
    }

    float ls = fmaxf(logit_scale[0], 0.01f);
#pragma unroll
    for (int mi = 0; mi < 4; ++mi) {
#pragma unroll
        for (int ni = 0; ni < 4; ++ni) {
            int col = m0 + wc*64 + ni*16 + l15;
#pragma unroll
            for (int j = 0; j < 4; ++j) {
                int row = n0 + wr*64 + mi*16 + lg*4 + j;
                float v = acc[mi][ni][j];
                if (row == col) v += dvec[(size_t)b*NN + row];
                __builtin_nontemporal_store(v * ls,
                    &out[((size_t)b*NN + row)*NN + col]);
            }
        }
    }
}

extern "C" void kernel_launch(void* const* d_in, const int* in_sizes, int n_in,
                              void* d_out, int out_size, void* d_ws, size_t ws_size,
                              hipStream_t stream)
{
    const float* feats = (const float*)d_in[0];
    const float* Wq    = (const float*)d_in[1];
    const float* Wk    = (const float*)d_in[2];
    const float* Wpi   = (const float*)d_in[3];
    const float* bpi   = (const float*)d_in[4];
    const float* Wpj   = (const float*)d_in[5];
    const float* bpj   = (const float*)d_in[6];
    const float* Wd    = (const float*)d_in[7];
    const float* bd    = (const float*)d_in[8];
    const float* alpha = (const float*)d_in[9];
    const float* lsc   = (const float*)d_in[10];

    char* ws = (char*)d_ws;
    __hip_bfloat16* xb = (__hip_bfloat16*)(ws);               // 8,388,608 B
    __hip_bfloat16* WT = (__hip_bfloat16*)(ws + 8388608);     //   229,376 B
    __hip_bfloat16* P  = (__hip_bfloat16*)(ws + 8617984);     // 7,340,032 B
    __hip_bfloat16* R  = (__hip_bfloat16*)(ws + 15958016);    // 7,340,032 B
    float*          dv = (float*)(ws + 23298048);             //    65,536 B

    k0_prep<<<1024, 256, 0, stream>>>(feats, Wq, Wk, Wpi, Wpj, Wd,
                                      xb, WT, (unsigned*)P, (unsigned*)R);
    ka_proj<<<512, 256, 0, stream>>>(xb, WT, bpi, bpj, bd, alpha, P, R, dv);
    kb_pair<<<2048, 256, 0, stream>>>(P, R, dv, lsc, (float*)d_out);
}

// Round 4
// 81.508 us; speedup vs baseline: 1.0155x; 1.0155x over previous
//
#include <hip/hip_runtime.h>
#include <hip/hip_bf16.h>
#include <stdint.h>

typedef __attribute__((ext_vector_type(8))) short short8;
typedef __attribute__((ext_vector_type(4))) float f32x4;
typedef __attribute__((ext_vector_type(4))) unsigned uint4v;

#define NB 8
#define NN 2048
#define CC 256
#define LP1 4097
#define HR 192
#define PDim 16
#define KP 224          /* padded K for pair GEMM: 208 real + 16 zero */
#define NPAD 448
#define HEAD_SCALE 0.17677669529663689f  /* 1/sqrt(32) */

#define GLOAD16(g, l) __builtin_amdgcn_global_load_lds( \
    (const __attribute__((address_space(1))) unsigned int*)(g), \
    (__attribute__((address_space(3))) unsigned int*)(l), 16, 0, 0)

// ---------------- K0: prep (vectorized) ----------------
__global__ __launch_bounds__(256) void k0_prep(
    const float* __restrict__ feats,
    const float* __restrict__ Wq, const float* __restrict__ Wk,
    const float* __restrict__ Wpi, const float* __restrict__ Wpj,
    const float* __restrict__ Wd,
    __hip_bfloat16* __restrict__ xb, __hip_bfloat16* __restrict__ WT,
    unsigned* __restrict__ Ppad, unsigned* __restrict__ Rpad)
{
    const int XV   = NB*NN*CC/8;   // 524288 short8 items
    const int WTN  = NPAD*CC;      // 114688
    const int PV   = NB*NN*2;      // 32768 uint4 items per array
    const int TOT  = XV + WTN + 2*PV;
    int stride = gridDim.x * blockDim.x;
    for (int i = blockIdx.x*blockDim.x + threadIdx.x; i < TOT; i += stride) {
        if (i < XV) {
            int grow = i >> 5, kk = (i & 31) << 3;
            int b = grow >> 11, n = grow & (NN-1);
            size_t base = ((size_t)b*LP1 + 1 + 2*n)*CC + kk;
            float4 a0 = *(const float4*)(feats + base);
            float4 a1 = *(const float4*)(feats + base + 4);
            float4 c0 = *(const float4*)(feats + base + CC);
            float4 c1 = *(const float4*)(feats + base + CC + 4);
            __hip_bfloat16 h[8];
            h[0] = __float2bfloat16(0.5f*(a0.x + c0.x));
            h[1] = __float2bfloat16(0.5f*(a0.y + c0.y));
            h[2] = __float2bfloat16(0.5f*(a0.z + c0.z));
            h[3] = __float2bfloat16(0.5f*(a0.w + c0.w));
            h[4] = __float2bfloat16(0.5f*(a1.x + c1.x));
            h[5] = __float2bfloat16(0.5f*(a1.y + c1.y));
            h[6] = __float2bfloat16(0.5f*(a1.z + c1.z));
            h[7] = __float2bfloat16(0.5f*(a1.w + c1.w));
            *(short8*)(xb + (size_t)grow*CC + kk) = *(const short8*)h;
        } else if (i < XV + WTN) {
            int j = i - XV;
            int c = j >> 8, k = j & 255;
            float v;
            if (c < HR)                 v = Wq[k*HR + c] * HEAD_SCALE;
            else if (c < 2*HR)          v = Wk[k*HR + (c-HR)];
            else if (c < 2*HR+PDim)     v = Wpi[k*PDim + (c-2*HR)];
            else if (c < 2*HR+2*PDim)   v = Wpj[k*PDim + (c-2*HR-PDim)];
            else if (c == 416)          v = Wd[k];
            else                        v = 0.f;
            WT[j] = __float2bfloat16(v);
        } else {
            int j = i - XV - WTN;
            unsigned* arr = (j < PV) ? Ppad : Rpad;
            int q = (j < PV) ? j : j - PV;
            int row = q >> 1, of = 104 + (q & 1)*4;   // uint cols [104,112)
            *(uint4v*)(arr + (size_t)row*(KP/2) + of) = (uint4v){0,0,0,0};
        }
    }
}

// ---------------- KA: projection GEMM ----------------
// (16384 x 256) x (256 x 448). Block = 32 rows x 448 cols, 512 blocks.
__global__ __launch_bounds__(256, 4) void ka_proj(
    const __hip_bfloat16* __restrict__ xb, const __hip_bfloat16* __restrict__ WT,
    const float* __restrict__ bpi, const float* __restrict__ bpj,
    const float* __restrict__ bd, const float* __restrict__ alpha_pair,
    __hip_bfloat16* __restrict__ P, __hip_bfloat16* __restrict__ R,
    float* __restrict__ dvec)
{
    int t = threadIdx.x;
    int lane = t & 63;
    int w = t >> 6;
    int l15 = lane & 15, lg = lane >> 4;
    int row0 = blockIdx.x * 32;

    const __hip_bfloat16* pA[2];
    const __hip_bfloat16* pB[7];
#pragma unroll
    for (int mi = 0; mi < 2; ++mi)
        pA[mi] = xb + (size_t)(row0 + mi*16 + l15)*CC + lg*8;
#pragma unroll
    for (int ni = 0; ni < 7; ++ni)
        pB[ni] = WT + (size_t)(w*112 + ni*16 + l15)*CC + lg*8;

    f32x4 acc[2][7];
#pragma unroll
    for (int mi = 0; mi < 2; ++mi)
#pragma unroll
        for (int ni = 0; ni < 7; ++ni)
            acc[mi][ni] = (f32x4){0.f, 0.f, 0.f, 0.f};

#pragma unroll
    for (int kk = 0; kk < 8; ++kk) {
        short8 a[2], bb[7];
#pragma unroll
        for (int mi = 0; mi < 2; ++mi) a[mi] = *(const short8*)(pA[mi] + kk*32);
#pragma unroll
        for (int ni = 0; ni < 7; ++ni) bb[ni] = *(const short8*)(pB[ni] + kk*32);
#pragma unroll
        for (int mi = 0; mi < 2; ++mi)
#pragma unroll
            for (int ni = 0; ni < 7; ++ni)
                acc[mi][ni] = __builtin_amdgcn_mfma_f32_16x16x32_bf16(
                    a[mi], bb[ni], acc[mi][ni], 0, 0, 0);
    }

    float alpha_eff = fmaxf(alpha_pair[0], 0.f);
    float bd0 = bd[0];
#pragma unroll
    for (int mi = 0; mi < 2; ++mi) {
#pragma unroll
        for (int ni = 0; ni < 7; ++ni) {
            int c = w*112 + ni*16 + l15;
#pragma unroll
            for (int j = 0; j < 4; ++j) {
                int r = mi*16 + lg*4 + j;
                int grow = row0 + r;
                int b = grow >> 11, n = grow & (NN-1);
                size_t rb = ((size_t)b*NN + n)*KP;
                float v = acc[mi][ni][j];
                if (c < HR) {
                    P[rb + c] = __float2bfloat16(v);           // Q*HEAD_SCALE (in WT)
                } else if (c < 2*HR) {
                    R[rb + (c-HR)] = __float2bfloat16(v);      // K
                } else if (c < 2*HR+PDim) {
                    int pc = c - 2*HR;
                    P[rb + HR + pc] = __float2bfloat16(fmaxf(v + bpi[pc], 0.f) * alpha_eff);
                } else if (c < 2*HR+2*PDim) {
                    int pc = c - 2*HR - PDim;
                    R[rb + HR + pc] = __float2bfloat16(fmaxf(v + bpj[pc], 0.f));
                } else if (c == 416) {
                    dvec[(size_t)b*NN + n] = v + bd0;
                }
            }
        }
    }
}

// ---------------- KB: batched pair GEMM ----------------
// S[b] = P[b] (2048x224) x R[b]^T + diag(d), * max(logit_scale,0.01).
// Swapped-operand MFMA: acc[ni][mi] = mfma(R_frag, P_frag, .) so each lane's
// 4 acc regs are 4 CONSECUTIVE output columns -> float4 NT stores.
__global__ __launch_bounds__(256, 4) void kb_pair(
    const __hip_bfloat16* __restrict__ P, const __hip_bfloat16* __restrict__ R,
    const float* __restrict__ dvec, const float* __restrict__ logit_scale,
    float* __restrict__ out)
{
    __shared__ __hip_bfloat16 ldsA[2][128*32];
    __shared__ __hip_bfloat16 ldsB[2][128*32];

    int t = threadIdx.x;
    int lane = t & 63;
    int w = t >> 6;
    int wr = w >> 1, wc = w & 1;
    int l15 = lane & 15, lg = lane >> 4;

    int hw = blockIdx.x;
    int b = hw & 7;                 // batch <-> XCD affinity
    int within = hw >> 3;           // 0..255
    int m0 = (within & 15) << 7;    // output cols (R rows)
    int n0 = (within >> 4) << 7;    // output rows (P rows)

    // staging source addrs (pre-swizzled). inst i: LDS byte = i*4096 + t*16
    // -> row = i*64 + (t>>2), colb = (t&3)*16; src colb = colb ^ ((row&3)<<4)
    const char* srcA[2];
    const char* srcB[2];
#pragma unroll
    for (int i = 0; i < 2; ++i) {
        int row   = i*64 + (t >> 2);
        int scolb = ((t & 3) << 4) ^ ((row & 3) << 4);
        srcA[i] = (const char*)(P + ((size_t)b*NN + n0 + row)*KP) + scolb;
        srcB[i] = (const char*)(R + ((size_t)b*NN + m0 + row)*KP) + scolb;
    }
    int ldst = w * 1024;   // wave-uniform LDS dest base (+ lane*16 by HW)

    // ds_read byte offsets (swizzled): row*64 + 16*(lg ^ (row&3)), + frag*1024
    int abyte = (wr*64 + l15)*64 + ((lg ^ (l15 & 3)) << 4);
    int bbyte = (wc*64 + l15)*64 + ((lg ^ (l15 & 3)) << 4);

    f32x4 acc[4][4];   // [ni][mi]
#pragma unroll
    for (int ni = 0; ni < 4; ++ni)
#pragma unroll
        for (int mi = 0; mi < 4; ++mi)
            acc[ni][mi] = (f32x4){0.f, 0.f, 0.f, 0.f};

    // prologue: stage K-step 0 into buf 0
#pragma unroll
    for (int i = 0; i < 2; ++i) {
        GLOAD16(srcA[i], (char*)(&ldsA[0][0]) + i*4096 + ldst);
        GLOAD16(srcB[i], (char*)(&ldsB[0][0]) + i*4096 + ldst);
    }

    int buf = 0;
#pragma unroll
    for (int s = 0; s < 7; ++s) {   // 7 K-steps of 32 (KP=224)
        __syncthreads();
        if (s < 6) {
            size_t kof = (size_t)(s + 1) * 64;
#pragma unroll
            for (int i = 0; i < 2; ++i) {
                GLOAD16(srcA[i] + kof, (char*)(&ldsA[buf ^ 1][0]) + i*4096 + ldst);
                GLOAD16(srcB[i] + kof, (char*)(&ldsB[buf ^ 1][0]) + i*4096 + ldst);
            }
        }
        short8 a[4], bb[4];
#pragma unroll
        for (int mi = 0; mi < 4; ++mi)
            a[mi] = *(const short8*)((const char*)(&ldsA[buf][0]) + abyte + mi*1024);
#pragma unroll
        for (int ni = 0; ni < 4; ++ni)
            bb[ni] = *(const short8*)((const char*)(&ldsB[buf][0]) + bbyte + ni*1024);
#pragma unroll
        for (int ni = 0; ni < 4; ++ni)
#pragma unroll
            for (int mi = 0; mi < 4; ++mi)
                acc[ni][mi] = __builtin_amdgcn_mfma_f32_16x16x32_bf16(
                    bb[ni], a[mi], acc[ni][mi], 0, 0, 0);
        buf ^= 1;
    }

    float ls = fmaxf(logit_scale[0], 0.01f);
    bool diag_tile = (n0 == m0);
#pragma unroll
    for (int ni = 0; ni < 4; ++ni) {
#pragma unroll
        for (int mi = 0; mi < 4; ++mi) {
            int orow  = n0 + wr*64 + mi*16 + l15;            // D col -> out row
            int cbase = m0 + wc*64 + ni*16 + lg*4;           // D rows -> out cols
            f32x4 v = acc[ni][mi];
            if (diag_tile) {
                int dj = orow - cbase;
                if (dj >= 0 && dj < 4) v[dj] += dvec[(size_t)b*NN + orow];
            }
            f32x4 o;
#pragma unroll
            for (int j = 0; j < 4; ++j) o[j] = v[j] * ls;
            __builtin_nontemporal_store(o,
                (f32x4*)(out + ((size_t)b*NN + orow)*NN + cbase));
        }
    }
}

extern "C" void kernel_launch(void* const* d_in, const int* in_sizes, int n_in,
                              void* d_out, int out_size, void* d_ws, size_t ws_size,
                              hipStream_t stream)
{
    const float* feats = (const float*)d_in[0];
    const float* Wq    = (const float*)d_in[1];
    const float* Wk    = (const float*)d_in[2];
    const float* Wpi   = (const float*)d_in[3];
    const float* bpi   = (const float*)d_in[4];
    const float* Wpj   = (const float*)d_in[5];
    const float* bpj   = (const float*)d_in[6];
    const float* Wd    = (const float*)d_in[7];
    const float* bd    = (const float*)d_in[8];
    const float* alpha = (const float*)d_in[9];
    const float* lsc   = (const float*)d_in[10];

    char* ws = (char*)d_ws;
    __hip_bfloat16* xb = (__hip_bfloat16*)(ws);               // 8,388,608 B
    __hip_bfloat16* WT = (__hip_bfloat16*)(ws + 8388608);     //   229,376 B
    __hip_bfloat16* P  = (__hip_bfloat16*)(ws + 8617984);     // 7,340,032 B
    __hip_bfloat16* R  = (__hip_bfloat16*)(ws + 15958016);    // 7,340,032 B
    float*          dv = (float*)(ws + 23298048);             //    65,536 B

    k0_prep<<<1024, 256, 0, stream>>>(feats, Wq, Wk, Wpi, Wpj, Wd,
                                      xb, WT, (unsigned*)P, (unsigned*)R);
    ka_proj<<<512, 256, 0, stream>>>(xb, WT, bpi, bpj, bd, alpha, P, R, dv);
    kb_pair<<<2048, 256, 0, stream>>>(P, R, dv, lsc, (float*)d_out);
}

// Round 5
// 69.939 us; speedup vs baseline: 1.1834x; 1.1654x over previous
//
#include <hip/hip_runtime.h>
#include <hip/hip_bf16.h>
#include <stdint.h>

typedef __attribute__((ext_vector_type(8))) short short8;
typedef __attribute__((ext_vector_type(4))) short short4v;
typedef __attribute__((ext_vector_type(4))) float f32x4;
typedef __attribute__((ext_vector_type(4))) unsigned uint4v;

#define NB 8
#define NN 2048
#define CC 256
#define LP1 4097
#define HR 192
#define PDim 16
#define KP 224          /* padded K for pair GEMM: 208 real + 16 zero */
#define NPAD 448
#define HEAD_SCALE 0.17677669529663689f  /* 1/sqrt(32) */

#define GLOAD16(g, l) __builtin_amdgcn_global_load_lds( \
    (const __attribute__((address_space(1))) unsigned int*)(g), \
    (__attribute__((address_space(3))) unsigned int*)(l), 16, 0, 0)

static __device__ __forceinline__ unsigned short bf16bits(float f) {
    __hip_bfloat16 h = __float2bfloat16(f);
    return *(unsigned short*)&h;
}

// ---------------- K0: WT + K-pad only ----------------
// WT (448 x 256 bf16, Q pre-scaled); zero-fill P/R K-pad cols [208,224).
__global__ __launch_bounds__(256) void k0_prep(
    const float* __restrict__ Wq, const float* __restrict__ Wk,
    const float* __restrict__ Wpi, const float* __restrict__ Wpj,
    const float* __restrict__ Wd,
    __hip_bfloat16* __restrict__ WT,
    unsigned* __restrict__ Ppad, unsigned* __restrict__ Rpad)
{
    const int WTN = NPAD*CC;       // 114688
    const int PV  = NB*NN*2;       // 32768 uint4 items per array
    int i = blockIdx.x*blockDim.x + threadIdx.x;   // grid 704*256 = TOT exactly
    if (i < WTN) {
        int c = i >> 8, k = i & 255;
        float v;
        if (c < HR)                 v = Wq[k*HR + c] * HEAD_SCALE;
        else if (c < 2*HR)          v = Wk[k*HR + (c-HR)];
        else if (c < 2*HR+PDim)     v = Wpi[k*PDim + (c-2*HR)];
        else if (c < 2*HR+2*PDim)   v = Wpj[k*PDim + (c-2*HR-PDim)];
        else if (c == 416)          v = Wd[k];
        else                        v = 0.f;
        WT[i] = __float2bfloat16(v);
    } else {
        int j = i - WTN;
        unsigned* arr = (j < PV) ? Ppad : Rpad;
        int q = (j < PV) ? j : j - PV;
        int row = q >> 1, of = 104 + (q & 1)*4;   // uint cols [104,112)
        *(uint4v*)(arr + (size_t)row*(KP/2) + of) = (uint4v){0,0,0,0};
    }
}

// ---------------- KA: fused fold + projection GEMM ----------------
// Per block: 32 x-rows. Stage fold(feats) -> bf16 LDS A-tile (XOR-swizzled),
// then (32 x 256) x (256 x 448) with swapped-operand MFMA so each lane holds
// 4 consecutive output cols of one row -> short4 stores into P/R.
__global__ __launch_bounds__(256, 3) void ka_proj(
    const float* __restrict__ feats, const __hip_bfloat16* __restrict__ WT,
    const float* __restrict__ bpi, const float* __restrict__ bpj,
    const float* __restrict__ bd, const float* __restrict__ alpha_pair,
    __hip_bfloat16* __restrict__ P, __hip_bfloat16* __restrict__ R,
    float* __restrict__ dvec)
{
    __shared__ __hip_bfloat16 lds[32*256];   // 16 KB A-tile

    int t = threadIdx.x;
    int lane = t & 63;
    int w = t >> 6;
    int l15 = lane & 15, lg = lane >> 4;
    int row0 = blockIdx.x * 32;              // global x-row base
    int b = row0 >> 11;                      // whole block inside one batch
    int n0loc = row0 & (NN-1);

    // ---- stage: fold 64 feats rows -> 32 bf16 rows in LDS ----
    {
        int r = t >> 3, cg = t & 7;          // r: 0..31 row, cg: 32-col group
        size_t fb = ((size_t)b*LP1 + 1 + 2*(size_t)(n0loc + r))*CC + cg*32;
#pragma unroll
        for (int s = 0; s < 4; ++s) {
            float4 a0 = *(const float4*)(feats + fb + s*8);
            float4 a1 = *(const float4*)(feats + fb + s*8 + 4);
            float4 c0 = *(const float4*)(feats + fb + CC + s*8);
            float4 c1 = *(const float4*)(feats + fb + CC + s*8 + 4);
            unsigned short h[8];
            h[0] = bf16bits(0.5f*(a0.x + c0.x));
            h[1] = bf16bits(0.5f*(a0.y + c0.y));
            h[2] = bf16bits(0.5f*(a0.z + c0.z));
            h[3] = bf16bits(0.5f*(a0.w + c0.w));
            h[4] = bf16bits(0.5f*(a1.x + c1.x));
            h[5] = bf16bits(0.5f*(a1.y + c1.y));
            h[6] = bf16bits(0.5f*(a1.z + c1.z));
            h[7] = bf16bits(0.5f*(a1.w + c1.w));
            int slot = (cg*4 + s) ^ (r & 7);
            *(short8*)((char*)lds + r*512 + slot*16) = *(const short8*)h;
        }
    }
    __syncthreads();

    // ---- GEMM ----
    const __hip_bfloat16* pB[7];
#pragma unroll
    for (int ni = 0; ni < 7; ++ni)
        pB[ni] = WT + (size_t)(w*112 + ni*16 + l15)*CC + lg*8;

    f32x4 acc[7][2];   // [ni][mi]
#pragma unroll
    for (int ni = 0; ni < 7; ++ni)
#pragma unroll
        for (int mi = 0; mi < 2; ++mi)
            acc[ni][mi] = (f32x4){0.f, 0.f, 0.f, 0.f};

    int arow[2];       // LDS row byte base per mi
#pragma unroll
    for (int mi = 0; mi < 2; ++mi) arow[mi] = (mi*16 + l15)*512;
    int rx = l15 & 7;  // row XOR key

#pragma unroll
    for (int kk = 0; kk < 8; ++kk) {
        short8 a[2], bb[7];
        int slotb = ((kk*4 + lg) ^ rx) << 4;
#pragma unroll
        for (int mi = 0; mi < 2; ++mi)
            a[mi] = *(const short8*)((const char*)lds + arow[mi] + slotb);
#pragma unroll
        for (int ni = 0; ni < 7; ++ni) bb[ni] = *(const short8*)(pB[ni] + kk*32);
#pragma unroll
        for (int ni = 0; ni < 7; ++ni)
#pragma unroll
            for (int mi = 0; mi < 2; ++mi)
                acc[ni][mi] = __builtin_amdgcn_mfma_f32_16x16x32_bf16(
                    bb[ni], a[mi], acc[ni][mi], 0, 0, 0);
    }

    // ---- routed epilogue: lane holds 4 consecutive cols of one row ----
    float alpha_eff = fmaxf(alpha_pair[0], 0.f);
    float bd0 = bd[0];
#pragma unroll
    for (int ni = 0; ni < 7; ++ni) {
        int cb = w*112 + ni*16 + lg*4;
#pragma unroll
        for (int mi = 0; mi < 2; ++mi) {
            int n = n0loc + mi*16 + l15;
            size_t rb = ((size_t)b*NN + n)*KP;
            f32x4 v = acc[ni][mi];
            if (cb < HR) {
                short4v h;
#pragma unroll
                for (int j = 0; j < 4; ++j) h[j] = (short)bf16bits(v[j]);
                *(short4v*)(P + rb + cb) = h;                    // Q*scale
            } else if (cb < 2*HR) {
                short4v h;
#pragma unroll
                for (int j = 0; j < 4; ++j) h[j] = (short)bf16bits(v[j]);
                *(short4v*)(R + rb + (cb - HR)) = h;             // K
            } else if (cb < 2*HR + PDim) {
                int pc = cb - 2*HR;
                short4v h;
#pragma unroll
                for (int j = 0; j < 4; ++j)
                    h[j] = (short)bf16bits(fmaxf(v[j] + bpi[pc+j], 0.f) * alpha_eff);
                *(short4v*)(P + rb + HR + pc) = h;               // alpha*a_i
            } else if (cb < 2*HR + 2*PDim) {
                int pc = cb - 2*HR - PDim;
                short4v h;
#pragma unroll
                for (int j = 0; j < 4; ++j)
                    h[j] = (short)bf16bits(fmaxf(v[j] + bpj[pc+j], 0.f));
                *(short4v*)(R + rb + HR + pc) = h;               // b_j
            } else if (cb == 416) {
                dvec[(size_t)b*NN + n] = v[0] + bd0;             // d
            }
        }
    }
}

// ---------------- KB: batched pair GEMM ----------------
// S[b] = P[b] (2048x224) x R[b]^T + diag(d), * max(logit_scale,0.01).
// Swapped-operand MFMA -> float4 stores (plain cached, L2 write-combines).
__global__ __launch_bounds__(256, 4) void kb_pair(
    const __hip_bfloat16* __restrict__ P, const __hip_bfloat16* __restrict__ R,
    const float* __restrict__ dvec, const float* __restrict__ logit_scale,
    float* __restrict__ out)
{
    __shared__ __hip_bfloat16 ldsA[2][128*32];
    __shared__ __hip_bfloat16 ldsB[2][128*32];

    int t = threadIdx.x;
    int lane = t & 63;
    int w = t >> 6;
    int wr = w >> 1, wc = w & 1;
    int l15 = lane & 15, lg = lane >> 4;

    int hw = blockIdx.x;
    int b = hw & 7;                 // batch <-> XCD affinity
    int within = hw >> 3;           // 0..255
    int m0 = (within & 15) << 7;    // output cols (R rows)
    int n0 = (within >> 4) << 7;    // output rows (P rows)

    const char* srcA[2];
    const char* srcB[2];
#pragma unroll
    for (int i = 0; i < 2; ++i) {
        int row   = i*64 + (t >> 2);
        int scolb = ((t & 3) << 4) ^ ((row & 3) << 4);
        srcA[i] = (const char*)(P + ((size_t)b*NN + n0 + row)*KP) + scolb;
        srcB[i] = (const char*)(R + ((size_t)b*NN + m0 + row)*KP) + scolb;
    }
    int ldst = w * 1024;   // wave-uniform LDS dest base (+ lane*16 by HW)

    int abyte = (wr*64 + l15)*64 + ((lg ^ (l15 & 3)) << 4);
    int bbyte = (wc*64 + l15)*64 + ((lg ^ (l15 & 3)) << 4);

    f32x4 acc[4][4];   // [ni][mi]
#pragma unroll
    for (int ni = 0; ni < 4; ++ni)
#pragma unroll
        for (int mi = 0; mi < 4; ++mi)
            acc[ni][mi] = (f32x4){0.f, 0.f, 0.f, 0.f};

#pragma unroll
    for (int i = 0; i < 2; ++i) {
        GLOAD16(srcA[i], (char*)(&ldsA[0][0]) + i*4096 + ldst);
        GLOAD16(srcB[i], (char*)(&ldsB[0][0]) + i*4096 + ldst);
    }

    int buf = 0;
#pragma unroll
    for (int s = 0; s < 7; ++s) {   // 7 K-steps of 32 (KP=224)
        __syncthreads();
        if (s < 6) {
            size_t kof = (size_t)(s + 1) * 64;
#pragma unroll
            for (int i = 0; i < 2; ++i) {
                GLOAD16(srcA[i] + kof, (char*)(&ldsA[buf ^ 1][0]) + i*4096 + ldst);
                GLOAD16(srcB[i] + kof, (char*)(&ldsB[buf ^ 1][0]) + i*4096 + ldst);
            }
        }
        short8 a[4], bb[4];
#pragma unroll
        for (int mi = 0; mi < 4; ++mi)
            a[mi] = *(const short8*)((const char*)(&ldsA[buf][0]) + abyte + mi*1024);
#pragma unroll
        for (int ni = 0; ni < 4; ++ni)
            bb[ni] = *(const short8*)((const char*)(&ldsB[buf][0]) + bbyte + ni*1024);
#pragma unroll
        for (int ni = 0; ni < 4; ++ni)
#pragma unroll
            for (int mi = 0; mi < 4; ++mi)
                acc[ni][mi] = __builtin_amdgcn_mfma_f32_16x16x32_bf16(
                    bb[ni], a[mi], acc[ni][mi], 0, 0, 0);
        buf ^= 1;
    }

    float ls = fmaxf(logit_scale[0], 0.01f);
    bool diag_tile = (n0 == m0);
#pragma unroll
    for (int ni = 0; ni < 4; ++ni) {
#pragma unroll
        for (int mi = 0; mi < 4; ++mi) {
            int orow  = n0 + wr*64 + mi*16 + l15;            // D col -> out row
            int cbase = m0 + wc*64 + ni*16 + lg*4;           // D rows -> out cols
            f32x4 v = acc[ni][mi];
            if (diag_tile) {
                int dj = orow - cbase;
                if (dj >= 0 && dj < 4) v[dj] += dvec[(size_t)b*NN + orow];
            }
            f32x4 o;
#pragma unroll
            for (int j = 0; j < 4; ++j) o[j] = v[j] * ls;
            *(f32x4*)(out + ((size_t)b*NN + orow)*NN + cbase) = o;
        }
    }
}

extern "C" void kernel_launch(void* const* d_in, const int* in_sizes, int n_in,
                              void* d_out, int out_size, void* d_ws, size_t ws_size,
                              hipStream_t stream)
{
    const float* feats = (const float*)d_in[0];
    const float* Wq    = (const float*)d_in[1];
    const float* Wk    = (const float*)d_in[2];
    const float* Wpi   = (const float*)d_in[3];
    const float* bpi   = (const float*)d_in[4];
    const float* Wpj   = (const float*)d_in[5];
    const float* bpj   = (const float*)d_in[6];
    const float* Wd    = (const float*)d_in[7];
    const float* bd    = (const float*)d_in[8];
    const float* alpha = (const float*)d_in[9];
    const float* lsc   = (const float*)d_in[10];

    char* ws = (char*)d_ws;
    __hip_bfloat16* WT = (__hip_bfloat16*)(ws);               //   229,376 B
    __hip_bfloat16* P  = (__hip_bfloat16*)(ws + 229376);      // 7,340,032 B
    __hip_bfloat16* R  = (__hip_bfloat16*)(ws + 7569408);     // 7,340,032 B
    float*          dv = (float*)(ws + 14909440);             //    65,536 B

    k0_prep<<<704, 256, 0, stream>>>(Wq, Wk, Wpi, Wpj, Wd,
                                     WT, (unsigned*)P, (unsigned*)R);
    ka_proj<<<512, 256, 0, stream>>>(feats, WT, bpi, bpj, bd, alpha, P, R, dv);
    kb_pair<<<2048, 256, 0, stream>>>(P, R, dv, lsc, (float*)d_out);
}